// Round 3
// baseline (378.498 us; speedup 1.0000x reference)
//
#include <hip/hip_runtime.h>

static constexpr int N_ROWS = 524288;
static constexpr int C_COLS = 128;
static constexpr float CLIP_V = 1e-10f;
static constexpr int BLOCKS = 2048;   // 524288 threads = 1 row/thread
static constexpr int THREADS = 256;

__device__ __forceinline__ float block_reduce_sum(float v) {
    #pragma unroll
    for (int off = 32; off > 0; off >>= 1)
        v += __shfl_down(v, off, 64);
    __shared__ float s[THREADS / 64];
    const int lane = threadIdx.x & 63;
    const int wave = threadIdx.x >> 6;
    if (lane == 0) s[wave] = v;
    __syncthreads();
    if (wave == 0) {
        v = (lane < THREADS / 64) ? s[lane] : 0.0f;
        #pragma unroll
        for (int off = (THREADS / 64) / 2; off > 0; off >>= 1)
            v += __shfl_down(v, off, 64);
    }
    return v; // valid in threadIdx.x == 0
}

// ws layout: ws[0] = float accumulator, ws[1] = finished-block counter (uint)
__global__ __launch_bounds__(THREADS)
void logloss_fused(const float* __restrict__ inp,
                   const int* __restrict__ tgt,
                   const float* __restrict__ w,
                   float* __restrict__ ws_acc,
                   unsigned* __restrict__ ws_cnt,
                   float* __restrict__ out) {
    __shared__ float wsm[C_COLS];
    for (int j = threadIdx.x; j < C_COLS; j += THREADS) wsm[j] = w[j];
    __syncthreads();

    const int tid = blockIdx.x * THREADS + threadIdx.x;
    const int stride = gridDim.x * THREADS;

    float acc = 0.0f;
    for (int i = tid; i < N_ROWS; i += stride) {
        const int t = tgt[i];                          // coalesced 4B/lane
        const float x = inp[(size_t)i * C_COLS + t];   // one 4B gather per row
        acc += __logf(fmaxf(x, CLIP_V)) * wsm[t];
    }

    const float b = block_reduce_sum(acc);
    if (threadIdx.x == 0) {
        atomicAdd(ws_acc, b);              // device-scope by default on gfx950
        __threadfence();                   // order acc-add before counter-add
        const unsigned done = atomicAdd(ws_cnt, 1u);
        if (done == (unsigned)(BLOCKS - 1)) {
            // all other blocks' acc-adds happened-before their counter-adds;
            // read via atomic to defeat any caching
            const float s = atomicAdd(ws_acc, 0.0f);
            out[0] = -s / (float)N_ROWS;
        }
    }
}

extern "C" void kernel_launch(void* const* d_in, const int* in_sizes, int n_in,
                              void* d_out, int out_size, void* d_ws, size_t ws_size,
                              hipStream_t stream) {
    const float* inp = (const float*)d_in[0];
    const int* tgt = (const int*)d_in[1];
    const float* w = (const float*)d_in[2];
    float* out = (float*)d_out;
    float* ws_acc = (float*)d_ws;
    unsigned* ws_cnt = (unsigned*)((char*)d_ws + sizeof(float));

    // zero the 8-byte accumulator+counter (ws is poisoned 0xAA each iteration)
    hipMemsetAsync(d_ws, 0, 2 * sizeof(float), stream);
    logloss_fused<<<BLOCKS, THREADS, 0, stream>>>(inp, tgt, w, ws_acc, ws_cnt, out);
}

// Round 4
// 315.443 us; speedup vs baseline: 1.1999x; 1.1999x over previous
//
#include <hip/hip_runtime.h>

static constexpr int N_ROWS = 524288;
static constexpr int C_COLS = 128;
static constexpr float CLIP_V = 1e-10f;
static constexpr int BLOCKS = 2048;   // 524288 threads = 1 row/thread
static constexpr int THREADS = 256;

__device__ __forceinline__ float block_reduce_sum(float v) {
    // 64-lane wave reduction (CDNA wave = 64)
    #pragma unroll
    for (int off = 32; off > 0; off >>= 1)
        v += __shfl_down(v, off, 64);
    __shared__ float s[THREADS / 64];
    const int lane = threadIdx.x & 63;
    const int wave = threadIdx.x >> 6;
    if (lane == 0) s[wave] = v;
    __syncthreads();
    if (wave == 0) {
        v = (lane < THREADS / 64) ? s[lane] : 0.0f;
        #pragma unroll
        for (int off = (THREADS / 64) / 2; off > 0; off >>= 1)
            v += __shfl_down(v, off, 64);
    }
    return v; // valid in threadIdx.x == 0
}

__global__ __launch_bounds__(THREADS)
void logloss_partial(const float* __restrict__ inp,
                     const int* __restrict__ tgt,
                     const float* __restrict__ w,
                     float* __restrict__ partial) {
    // stage weight[128] in LDS (512 B)
    __shared__ float ws[C_COLS];
    for (int j = threadIdx.x; j < C_COLS; j += THREADS) ws[j] = w[j];
    __syncthreads();

    const int tid = blockIdx.x * THREADS + threadIdx.x;
    const int stride = gridDim.x * THREADS;

    float acc = 0.0f; // sum of log(clip(x)) * w (negated at the end)
    for (int i = tid; i < N_ROWS; i += stride) {
        const int t = tgt[i];                          // coalesced 4B/lane
        const float x = inp[(size_t)i * C_COLS + t];   // one 4B gather per row
        acc += __logf(fmaxf(x, CLIP_V)) * ws[t];
    }

    const float b = block_reduce_sum(acc);
    if (threadIdx.x == 0) partial[blockIdx.x] = b;
}

__global__ __launch_bounds__(THREADS)
void logloss_final(const float* __restrict__ partial, float* __restrict__ out) {
    float v = 0.0f;
    for (int i = threadIdx.x; i < BLOCKS; i += THREADS) v += partial[i];
    const float s = block_reduce_sum(v);
    if (threadIdx.x == 0) out[0] = -s / (float)N_ROWS;
}

extern "C" void kernel_launch(void* const* d_in, const int* in_sizes, int n_in,
                              void* d_out, int out_size, void* d_ws, size_t ws_size,
                              hipStream_t stream) {
    const float* inp = (const float*)d_in[0];
    const int* tgt = (const int*)d_in[1];
    const float* w = (const float*)d_in[2];
    float* out = (float*)d_out;
    float* partial = (float*)d_ws; // BLOCKS * 4 bytes

    logloss_partial<<<BLOCKS, THREADS, 0, stream>>>(inp, tgt, w, partial);
    logloss_final<<<1, THREADS, 0, stream>>>(partial, out);
}